// Round 11
// baseline (244.473 us; speedup 1.0000x reference)
//
#include <hip/hip_runtime.h>
#include <hip/hip_bf16.h>
#include <hip/hip_cooperative_groups.h>

namespace cg = cooperative_groups;

// Problem constants: B=4, G=3, p=16, N=256, C=768, H=12, D=64
#define Bc 4
#define Gc 3
#define Nc 256
#define Cc_ 768
#define Dc 64
#define Mrows (Bc*Gc*Nc)      // 3072 tokens
#define QKVc (3*Cc_)          // 2304 fused output cols: [q | k | v]
#define Koff Cc_              // k starts at col 768
#define Voff (2*Cc_)          // v starts at col 1536

typedef _Float16 half_t;
typedef __attribute__((ext_vector_type(8))) _Float16 f16x8;
typedef __attribute__((ext_vector_type(4))) float f32x4;

#define XN   (Mrows*Cc_)      // 2359296
#define WQN  (Cc_*Cc_)        // 589824
#define WKVN (2*Cc_*Cc_)      // 1179648
#define PWN  (Cc_*Cc_)        // 589824
#define CVTN ((XN+WQN+WKVN+PWN)/8)   // 589824 vec8 chunks

#define QKV_TILES ((QKVc/128)*(Mrows/128))   // 18*24 = 432
#define PRJ_TILES ((Cc_/128)*(Mrows/128))    //  6*24 = 144

// 256 blocks = 1 block/CU: co-residency guaranteed for any launchable kernel
#define GRID_BLKS 256

__device__ __forceinline__ f16x8 cv8(const float4& x, const float4& y) {
    f16x8 o;
    o[0] = (half_t)x.x; o[1] = (half_t)x.y; o[2] = (half_t)x.z; o[3] = (half_t)x.w;
    o[4] = (half_t)y.x; o[5] = (half_t)y.y; o[6] = (half_t)y.z; o[7] = (half_t)y.w;
    return o;
}

// LDS: GEMM phases use the 48KB triple-buffer; attention aliases a small slice.
union ShMem {
    struct { half_t sm[3][2][4][128][8]; } g;   // 48 KiB
    struct { float qs[Cc_]; int rows[32]; } a;  // ~3.2 KiB
};

// ---------------------------------------------------------------------------
// f16 MFMA GEMM tile (round-6 verified structure, verbatim — do not perturb):
// C[m][n] = sum_k A[m][k]*W[n][k] (+bias). 128x128 tile, BK=32, 4 waves
// (2x2 of 64x64), mfma 16x16x32. 3 LDS buffers, stage 2 tiles ahead via
// global_load_lds(16B), counted s_waitcnt vmcnt(4) + raw s_barrier — never
// drains vmcnt(0) in the main loop. Stage(t+2) issued AFTER the barrier.
// Safe back-to-back per block: tile ends on buf (NT-1)%3=2; the next tile's
// prologue writes bufs 0/1 and its first vmcnt+barrier re-aligns all waves.
// ---------------------------------------------------------------------------
template<typename OutT, bool BIAS>
__device__ __forceinline__ void gemm_tile(
    ShMem& shm,
    const half_t* __restrict__ A, const half_t* __restrict__ W,
    OutT* __restrict__ C, const float* __restrict__ bias,
    int m0, int n0, int Nn, int K)
{
    auto& sm = shm.g.sm;               // [buf][A/B][kgroup][row][8 f16]
    const int tid = threadIdx.x;
    const int w   = tid >> 6;          // wave 0..3
    const int l   = tid & 63;
    const int wm  = w >> 1;            // m sub-tile
    const int wn  = w & 1;             // n sub-tile

    f32x4 acc[4][4] = {};

    auto stage = [&](int buf, int k0) {
        #pragma unroll
        for (int i = 0; i < 2; ++i) {
            const int c   = w * 2 + i;
            const int kg  = c >> 1;
            const int r0  = (c & 1) * 64;
            const half_t* ga = A + (size_t)(m0 + r0 + l) * K + k0 + kg * 8;
            const half_t* gb = W + (size_t)(n0 + r0 + l) * K + k0 + kg * 8;
            __builtin_amdgcn_global_load_lds(
                (__attribute__((address_space(1))) void*)ga,
                (__attribute__((address_space(3))) void*)&sm[buf][0][kg][r0][0],
                16, 0, 0);
            __builtin_amdgcn_global_load_lds(
                (__attribute__((address_space(1))) void*)gb,
                (__attribute__((address_space(3))) void*)&sm[buf][1][kg][r0][0],
                16, 0, 0);
        }
    };

    const int NT = K >> 5;             // 24 for K=768
    stage(0, 0);
    stage(1, 32);

    const int kg = l >> 4;             // 0..3
    const int lr = l & 15;
    int cur = 0;

    for (int t = 0; t < NT; ++t) {
        // retire exactly stage(t) (own wave's 4 loads), keep t+1 in flight
        if (t + 1 < NT) asm volatile("s_waitcnt vmcnt(4)" ::: "memory");
        else            asm volatile("s_waitcnt vmcnt(0)" ::: "memory");
        __builtin_amdgcn_s_barrier();
        if (t + 2 < NT) {
            int nb = cur + 2; if (nb >= 3) nb -= 3;
            stage(nb, (t + 2) << 5);
        }

        f16x8 af[4], bf[4];
        #pragma unroll
        for (int mi = 0; mi < 4; ++mi)
            af[mi] = *(const f16x8*)&sm[cur][0][kg][wm * 64 + mi * 16 + lr][0];
        #pragma unroll
        for (int ni = 0; ni < 4; ++ni)
            bf[ni] = *(const f16x8*)&sm[cur][1][kg][wn * 64 + ni * 16 + lr][0];

        #pragma unroll
        for (int mi = 0; mi < 4; ++mi)
            #pragma unroll
            for (int ni = 0; ni < 4; ++ni)
                acc[mi][ni] = __builtin_amdgcn_mfma_f32_16x16x32_f16(
                    af[mi], bf[ni], acc[mi][ni], 0, 0, 0);

        cur = (cur == 2) ? 0 : cur + 1;
    }

    // epilogue: C/D layout col = lane&15, row = (lane>>4)*4 + reg (m89)
    const int lq = l >> 4;
    #pragma unroll
    for (int ni = 0; ni < 4; ++ni) {
        const int gcol = n0 + wn * 64 + ni * 16 + lr;
        const float bv = BIAS ? bias[gcol] : 0.f;
        #pragma unroll
        for (int mi = 0; mi < 4; ++mi) {
            const int grow = m0 + wm * 64 + mi * 16 + lq * 4;
            #pragma unroll
            for (int r = 0; r < 4; ++r)
                C[(size_t)(grow + r) * Nn + gcol] = (OutT)(acc[mi][ni][r] + bv);
        }
    }
}

// ---------------------------------------------------------------------------
// Attention for one token (round-6 verified body): 4 waves, wave handles
// heads {w, w+4, w+8}; K/V gathered from the fused QKV buffer via the
// triplane map. Trailing __syncthreads protects LDS reuse across tokens.
// ---------------------------------------------------------------------------
__device__ __forceinline__ void attn_token(
    ShMem& shm, const half_t* __restrict__ QKV, half_t* __restrict__ Oa, int t)
{
    float* qs   = shm.a.qs;
    int*   rows = shm.a.rows;

    const int g  = t >> 10;
    const int b  = (t >> 8) & 3;
    const int n  = t & 255;
    const int a  = n >> 4;
    const int bc = n & 15;

    const int qrow = (b * Gc + g) * Nc + n;
    if (threadIdx.x < 96) {
        const f16x8 v = ((const f16x8*)(QKV + (size_t)qrow * QKVc))[threadIdx.x];
        #pragma unroll
        for (int jj = 0; jj < 8; ++jj) qs[threadIdx.x * 8 + jj] = (float)v[jj];
    }
    if (threadIdx.x < 32) {
        const int j = threadIdx.x;
        int g1 = g + 1; if (g1 >= 3) g1 -= 3;
        int g2 = g + 2; if (g2 >= 3) g2 -= 3;
        rows[j] = (j < 16) ? ((b * Gc + g1) * Nc + a * 16 + j)
                           : ((b * Gc + g2) * Nc + (j - 16) * 16 + bc);
    }
    __syncthreads();

    const int wave = threadIdx.x >> 6;
    const int lane = threadIdx.x & 63;
    const int j    = lane & 31;
    const int dh   = lane >> 5;
    const size_t kvrow = (size_t)rows[j] * QKVc;

    for (int hh = 0; hh < 3; ++hh) {
        const int h = wave + hh * 4;
        // ---- scores: lane=(j ctx, dh half), vectorized f16 K reads ----
        const f16x8* kp = (const f16x8*)(QKV + kvrow + Koff + h * Dc + dh * 32);
        const float* qp = qs + h * Dc + dh * 32;
        float s = 0.f;
        #pragma unroll
        for (int c = 0; c < 4; ++c) {
            const f16x8 k8 = kp[c];
            #pragma unroll
            for (int e = 0; e < 8; ++e) s = fmaf(qp[c * 8 + e], (float)k8[e], s);
        }
        s += __shfl_xor(s, 32);
        s *= 0.125f;                         // 1/sqrt(64)

        // ---- softmax over 32 ctx (halves identical) ----
        float m = s;
        #pragma unroll
        for (int off = 16; off >= 1; off >>= 1) m = fmaxf(m, __shfl_xor(m, off));
        const float e = __expf(s - m);
        float lsum = e;
        #pragma unroll
        for (int off = 16; off >= 1; off >>= 1) lsum += __shfl_xor(lsum, off);
        const float pr = e / lsum;

        // ---- PV: lane = output dim ----
        float o = 0.f;
        #pragma unroll 8
        for (int jj = 0; jj < 32; ++jj) {
            const float pj = __shfl(pr, jj);
            o = fmaf(pj, (float)QKV[(size_t)rows[jj] * QKVc + Voff + h * Dc + lane], o);
        }
        Oa[(size_t)t * Cc_ + h * Dc + lane] = (half_t)o;
    }
    __syncthreads();   // qs/rows reused by next token in the loop
}

// ---------------------------------------------------------------------------
// Device-side cvt body (shared by fused phase 0 and the fallback kernel)
// ---------------------------------------------------------------------------
__device__ __forceinline__ void cvt_chunk(
    size_t e, const float* __restrict__ x, const float* __restrict__ wq,
    const float* __restrict__ wkv, const float* __restrict__ pw,
    half_t* __restrict__ x16, half_t* __restrict__ w3,
    half_t* __restrict__ pw16)
{
    const float* s; half_t* d;
    if (e < XN)                    { s = x   + e;                     d = x16  + e; }
    else if (e < XN + WQN)         { s = wq  + (e - XN);              d = w3   + (e - XN); }
    else if (e < XN + WQN + WKVN)  { s = wkv + (e - XN - WQN);        d = w3 + WQN + (e - XN - WQN); }
    else                           { s = pw  + (e - XN - WQN - WKVN); d = pw16 + (e - XN - WQN - WKVN); }
    const float4 a4 = *(const float4*)s;
    const float4 b4 = *(const float4*)(s + 4);
    *(f16x8*)d = cv8(a4, b4);
}

// ---------------------------------------------------------------------------
// ONE cooperative persistent kernel (grid-stride in every phase — grid-size
// agnostic): cvt -> grid.sync -> QKV GEMM -> grid.sync -> attention ->
// grid.sync -> proj GEMM. Removes 3 dispatch boundaries.
// ---------------------------------------------------------------------------
__global__ __launch_bounds__(256) void fused_all(
    const float* __restrict__ x,  const float* __restrict__ wq,
    const float* __restrict__ wkv, const float* __restrict__ pw,
    const float* __restrict__ pb, float* __restrict__ out,
    half_t* __restrict__ ws)
{
    __shared__ ShMem shm;

    half_t* x16   = ws;
    half_t* w3    = x16 + XN;                      // [wq; wkv] = (2304, 768)
    half_t* pw16  = w3 + WQN + WKVN;
    half_t* QKV16 = pw16 + PWN;                    // (3072, 2304)
    half_t* ATT16 = QKV16 + (size_t)Mrows * QKVc;  // (3072, 768)

    const int nb  = gridDim.x;
    const int bid = blockIdx.x;

    // ---- phase 0: fp32 -> f16 for x + all weights ----
    for (size_t v = (size_t)bid * 256 + threadIdx.x; v < CVTN; v += (size_t)nb * 256)
        cvt_chunk(v * 8, x, wq, wkv, pw, x16, w3, pw16);

    cg::this_grid().sync();

    // ---- phase 1: QKV = x16 @ [wq;wkv]^T, 432 tiles ----
    for (int tile = bid; tile < QKV_TILES; tile += nb) {
        const int bx = tile % (QKVc / 128);
        const int by = tile / (QKVc / 128);
        gemm_tile<half_t, false>(shm, x16, w3, QKV16, nullptr,
                                 by * 128, bx * 128, QKVc, Cc_);
        __syncthreads();
    }

    cg::this_grid().sync();

    // ---- phase 2: attention, 12 tokens per block at 256 blocks ----
    for (int t = bid; t < Mrows; t += nb)
        attn_token(shm, QKV16, ATT16, t);

    cg::this_grid().sync();

    // ---- phase 3: out = ATT16 @ pw16^T + pb, 144 tiles ----
    for (int tile = bid; tile < PRJ_TILES; tile += nb) {
        const int bx = tile % (Cc_ / 128);
        const int by = tile / (Cc_ / 128);
        gemm_tile<float, true>(shm, ATT16, pw16, out, pb,
                               by * 128, bx * 128, Cc_, Cc_);
        __syncthreads();
    }
}

// ---------------------------------------------------------------------------
// Fallback path: round-6 verbatim 4-kernel pipeline (85.5us known-good),
// used only if the cooperative launch is rejected by the runtime.
// ---------------------------------------------------------------------------
__global__ __launch_bounds__(256) void cvt_all(
    const float* __restrict__ x, const float* __restrict__ wq,
    const float* __restrict__ wkv, const float* __restrict__ pw,
    half_t* __restrict__ x16, half_t* __restrict__ w3,
    half_t* __restrict__ pw16)
{
    cvt_chunk(((size_t)blockIdx.x * 256 + threadIdx.x) * 8,
              x, wq, wkv, pw, x16, w3, pw16);
}

template<typename OutT, bool BIAS>
__global__ __launch_bounds__(256) void gemm16(
    const half_t* __restrict__ A, const half_t* __restrict__ W,
    OutT* __restrict__ C, const float* __restrict__ bias,
    int M, int Nn, int K)
{
    __shared__ ShMem shm;
    gemm_tile<OutT, BIAS>(shm, A, W, C, bias,
                          blockIdx.y << 7, blockIdx.x << 7, Nn, K);
}

__global__ __launch_bounds__(256) void attn_kernel(
    const half_t* __restrict__ QKV, half_t* __restrict__ Oa)
{
    __shared__ ShMem shm;
    attn_token(shm, QKV, Oa, blockIdx.x);
}

extern "C" void kernel_launch(void* const* d_in, const int* in_sizes, int n_in,
                              void* d_out, int out_size, void* d_ws, size_t ws_size,
                              hipStream_t stream) {
    const float* x   = (const float*)d_in[0];
    const float* wq  = (const float*)d_in[1];
    const float* wkv = (const float*)d_in[2];
    const float* pw  = (const float*)d_in[3];
    const float* pb  = (const float*)d_in[4];
    float* out = (float*)d_out;
    half_t* ws = (half_t*)d_ws;

    void* args[] = { (void*)&x, (void*)&wq, (void*)&wkv, (void*)&pw,
                     (void*)&pb, (void*)&out, (void*)&ws };
    hipError_t rc = hipLaunchCooperativeKernel(
        (const void*)fused_all, dim3(GRID_BLKS), dim3(256), args, 0, stream);

    if (rc != hipSuccess) {
        // r6-verbatim fallback (85.5us known-good), same ws layout
        half_t* x16   = ws;
        half_t* w3    = x16 + XN;
        half_t* pw16  = w3 + WQN + WKVN;
        half_t* QKV16 = pw16 + PWN;
        half_t* ATT16 = QKV16 + (size_t)Mrows * QKVc;
        const dim3 blk(256);
        cvt_all<<<dim3(CVTN / 256), blk, 0, stream>>>(
            x, wq, wkv, pw, x16, w3, pw16);
        gemm16<half_t, false><<<dim3(QKVc / 128, Mrows / 128), blk, 0, stream>>>(
            x16, w3, QKV16, nullptr, Mrows, QKVc, Cc_);
        attn_kernel<<<dim3(Mrows), blk, 0, stream>>>(QKV16, ATT16);
        gemm16<float, true><<<dim3(Cc_ / 128, Mrows / 128), blk, 0, stream>>>(
            ATT16, pw16, out, pb, Mrows, Cc_, Cc_);
    }
}

// Round 12
// 95.416 us; speedup vs baseline: 2.5622x; 2.5622x over previous
//
#include <hip/hip_runtime.h>
#include <hip/hip_bf16.h>

// Problem constants: B=4, G=3, p=16, N=256, C=768, H=12, D=64
#define Bc 4
#define Gc 3
#define Nc 256
#define Cc_ 768
#define Dc 64
#define Mrows (Bc*Gc*Nc)      // 3072 tokens
#define QKVc (3*Cc_)          // 2304 fused output cols: [q | k | v]
#define Koff Cc_              // k starts at col 768
#define Voff (2*Cc_)          // v starts at col 1536

typedef _Float16 half_t;
typedef __attribute__((ext_vector_type(8))) _Float16 f16x8;
typedef __attribute__((ext_vector_type(4))) float f32x4;

#define XN   (Mrows*Cc_)      // 2359296
#define WQN  (Cc_*Cc_)        // 589824
#define WKVN (2*Cc_*Cc_)      // 1179648
#define PWN  (Cc_*Cc_)        // 589824
#define CVTN ((XN+WQN+WKVN+PWN)/8)   // 589824 vec8 chunks

#define NXCD 8

__device__ __forceinline__ f16x8 cv8(const float4& x, const float4& y) {
    f16x8 o;
    o[0] = (half_t)x.x; o[1] = (half_t)x.y; o[2] = (half_t)x.z; o[3] = (half_t)x.w;
    o[4] = (half_t)y.x; o[5] = (half_t)y.y; o[6] = (half_t)y.z; o[7] = (half_t)y.w;
    return o;
}

// LDS: GEMM uses the 48KB triple-buffer; attention aliases a small slice.
union ShMem {
    struct { half_t sm[3][2][4][128][8]; } g;   // 48 KiB
    struct { float qs[Cc_]; int rows[32]; } a;  // ~3.2 KiB
};

// ---------------------------------------------------------------------------
// f16 MFMA GEMM tile (round-6 verified structure, verbatim — do not perturb):
// C[m][n] = sum_k A[m][k]*W[n][k] (+bias). 128x128 tile, BK=32, 4 waves
// (2x2 of 64x64), mfma 16x16x32. 3 LDS buffers, stage 2 tiles ahead via
// global_load_lds(16B), counted s_waitcnt vmcnt(4) + raw s_barrier — never
// drains vmcnt(0) in the main loop. Stage(t+2) issued AFTER the barrier.
// ---------------------------------------------------------------------------
template<typename OutT, bool BIAS>
__device__ __forceinline__ void gemm_tile(
    ShMem& shm,
    const half_t* __restrict__ A, const half_t* __restrict__ W,
    OutT* __restrict__ C, const float* __restrict__ bias,
    int m0, int n0, int Nn, int K)
{
    auto& sm = shm.g.sm;               // [buf][A/B][kgroup][row][8 f16]
    const int tid = threadIdx.x;
    const int w   = tid >> 6;          // wave 0..3
    const int l   = tid & 63;
    const int wm  = w >> 1;            // m sub-tile
    const int wn  = w & 1;             // n sub-tile

    f32x4 acc[4][4] = {};

    auto stage = [&](int buf, int k0) {
        #pragma unroll
        for (int i = 0; i < 2; ++i) {
            const int c   = w * 2 + i;
            const int kg  = c >> 1;
            const int r0  = (c & 1) * 64;
            const half_t* ga = A + (size_t)(m0 + r0 + l) * K + k0 + kg * 8;
            const half_t* gb = W + (size_t)(n0 + r0 + l) * K + k0 + kg * 8;
            __builtin_amdgcn_global_load_lds(
                (__attribute__((address_space(1))) void*)ga,
                (__attribute__((address_space(3))) void*)&sm[buf][0][kg][r0][0],
                16, 0, 0);
            __builtin_amdgcn_global_load_lds(
                (__attribute__((address_space(1))) void*)gb,
                (__attribute__((address_space(3))) void*)&sm[buf][1][kg][r0][0],
                16, 0, 0);
        }
    };

    const int NT = K >> 5;             // 24 for K=768
    stage(0, 0);
    stage(1, 32);

    const int kg = l >> 4;             // 0..3
    const int lr = l & 15;
    int cur = 0;

    for (int t = 0; t < NT; ++t) {
        // retire exactly stage(t) (own wave's 4 loads), keep t+1 in flight
        if (t + 1 < NT) asm volatile("s_waitcnt vmcnt(4)" ::: "memory");
        else            asm volatile("s_waitcnt vmcnt(0)" ::: "memory");
        __builtin_amdgcn_s_barrier();
        if (t + 2 < NT) {
            int nb = cur + 2; if (nb >= 3) nb -= 3;
            stage(nb, (t + 2) << 5);
        }

        f16x8 af[4], bf[4];
        #pragma unroll
        for (int mi = 0; mi < 4; ++mi)
            af[mi] = *(const f16x8*)&sm[cur][0][kg][wm * 64 + mi * 16 + lr][0];
        #pragma unroll
        for (int ni = 0; ni < 4; ++ni)
            bf[ni] = *(const f16x8*)&sm[cur][1][kg][wn * 64 + ni * 16 + lr][0];

        #pragma unroll
        for (int mi = 0; mi < 4; ++mi)
            #pragma unroll
            for (int ni = 0; ni < 4; ++ni)
                acc[mi][ni] = __builtin_amdgcn_mfma_f32_16x16x32_f16(
                    af[mi], bf[ni], acc[mi][ni], 0, 0, 0);

        cur = (cur == 2) ? 0 : cur + 1;
    }

    // epilogue: C/D layout col = lane&15, row = (lane>>4)*4 + reg (m89)
    const int lq = l >> 4;
    #pragma unroll
    for (int ni = 0; ni < 4; ++ni) {
        const int gcol = n0 + wn * 64 + ni * 16 + lr;
        const float bv = BIAS ? bias[gcol] : 0.f;
        #pragma unroll
        for (int mi = 0; mi < 4; ++mi) {
            const int grow = m0 + wm * 64 + mi * 16 + lq * 4;
            #pragma unroll
            for (int r = 0; r < 4; ++r)
                C[(size_t)(grow + r) * Nn + gcol] = (OutT)(acc[mi][ni][r] + bv);
        }
    }
}

// ---------------------------------------------------------------------------
// Attention for one token (round-6 verified body, verbatim): 4 waves, wave
// handles heads {w, w+4, w+8}; K/V gathered from the fused QKV buffer.
// ---------------------------------------------------------------------------
__device__ __forceinline__ void attn_token(
    ShMem& shm, const half_t* __restrict__ QKV, half_t* __restrict__ Oa, int t)
{
    float* qs   = shm.a.qs;
    int*   rows = shm.a.rows;

    const int g  = t >> 10;
    const int b  = (t >> 8) & 3;
    const int n  = t & 255;
    const int a  = n >> 4;
    const int bc = n & 15;

    const int qrow = (b * Gc + g) * Nc + n;
    if (threadIdx.x < 96) {
        const f16x8 v = ((const f16x8*)(QKV + (size_t)qrow * QKVc))[threadIdx.x];
        #pragma unroll
        for (int jj = 0; jj < 8; ++jj) qs[threadIdx.x * 8 + jj] = (float)v[jj];
    }
    if (threadIdx.x < 32) {
        const int j = threadIdx.x;
        int g1 = g + 1; if (g1 >= 3) g1 -= 3;
        int g2 = g + 2; if (g2 >= 3) g2 -= 3;
        rows[j] = (j < 16) ? ((b * Gc + g1) * Nc + a * 16 + j)
                           : ((b * Gc + g2) * Nc + (j - 16) * 16 + bc);
    }
    __syncthreads();

    const int wave = threadIdx.x >> 6;
    const int lane = threadIdx.x & 63;
    const int j    = lane & 31;
    const int dh   = lane >> 5;
    const size_t kvrow = (size_t)rows[j] * QKVc;

    for (int hh = 0; hh < 3; ++hh) {
        const int h = wave + hh * 4;
        // ---- scores: lane=(j ctx, dh half), vectorized f16 K reads ----
        const f16x8* kp = (const f16x8*)(QKV + kvrow + Koff + h * Dc + dh * 32);
        const float* qp = qs + h * Dc + dh * 32;
        float s = 0.f;
        #pragma unroll
        for (int c = 0; c < 4; ++c) {
            const f16x8 k8 = kp[c];
            #pragma unroll
            for (int e = 0; e < 8; ++e) s = fmaf(qp[c * 8 + e], (float)k8[e], s);
        }
        s += __shfl_xor(s, 32);
        s *= 0.125f;                         // 1/sqrt(64)

        // ---- softmax over 32 ctx (halves identical) ----
        float m = s;
        #pragma unroll
        for (int off = 16; off >= 1; off >>= 1) m = fmaxf(m, __shfl_xor(m, off));
        const float e = __expf(s - m);
        float lsum = e;
        #pragma unroll
        for (int off = 16; off >= 1; off >>= 1) lsum += __shfl_xor(lsum, off);
        const float pr = e / lsum;

        // ---- PV: lane = output dim ----
        float o = 0.f;
        #pragma unroll 8
        for (int jj = 0; jj < 32; ++jj) {
            const float pj = __shfl(pr, jj);
            o = fmaf(pj, (float)QKV[(size_t)rows[jj] * QKVc + Voff + h * Dc + lane], o);
        }
        Oa[(size_t)t * Cc_ + h * Dc + lane] = (half_t)o;
    }
}

// ---------------------------------------------------------------------------
// cvt: fp32 -> f16 for x + all three weights (r6-verbatim body)
// ---------------------------------------------------------------------------
__global__ __launch_bounds__(256) void cvt_all(
    const float* __restrict__ x, const float* __restrict__ wq,
    const float* __restrict__ wkv, const float* __restrict__ pw,
    half_t* __restrict__ x16, half_t* __restrict__ w3,
    half_t* __restrict__ pw16)
{
    const size_t e = ((size_t)blockIdx.x * 256 + threadIdx.x) * 8;
    const float* s; half_t* d;
    if (e < XN)                    { s = x   + e;                     d = x16  + e; }
    else if (e < XN + WQN)         { s = wq  + (e - XN);              d = w3   + (e - XN); }
    else if (e < XN + WQN + WKVN)  { s = wkv + (e - XN - WQN);        d = w3 + WQN + (e - XN - WQN); }
    else                           { s = pw  + (e - XN - WQN - WKVN); d = pw16 + (e - XN - WQN - WKVN); }
    const float4 a4 = *(const float4*)s;
    const float4 b4 = *(const float4*)(s + 4);
    *(f16x8*)d = cv8(a4, b4);
}

// ---------------------------------------------------------------------------
// GEMM wrapper with XCD-chunked bijective tile swizzle (T1, m192/m204):
// 1D grid, nb % 8 == 0 (432 and 144 both). tile = (bid%8)*(nb/8) + bid/8
// gives each XCD a CONTIGUOUS run of tiles -> per-XCD L2 working set =
// few A-panels + B ~= 4MB instead of the whole problem.
// ---------------------------------------------------------------------------
template<typename OutT, bool BIAS>
__global__ __launch_bounds__(256) void gemm16(
    const half_t* __restrict__ A, const half_t* __restrict__ W,
    OutT* __restrict__ C, const float* __restrict__ bias,
    int Nn, int K)
{
    __shared__ ShMem shm;
    const int nb    = gridDim.x;
    const int tile  = (blockIdx.x & (NXCD - 1)) * (nb >> 3) + (blockIdx.x >> 3);
    const int tpr   = Nn >> 7;                  // tiles per row panel
    const int by    = tile / tpr;
    const int bx    = tile - by * tpr;
    gemm_tile<OutT, BIAS>(shm, A, W, C, bias, by << 7, bx << 7, Nn, K);
}

// ---------------------------------------------------------------------------
// Attention wrapper with batch->XCD-pair swizzle: batch b's whole working
// set (Q 1.1MB + K/V 2.25MB ~= 3.4MB) fits ONE XCD's 4MB L2, but the default
// mapping spreads all 4 batches (13.6MB) over every XCD -> L2 thrash.
// bid&7 = xcd; xcd pair {2b,2b+1} serves batch b; 3072 = 8 * 384 exactly.
// Bijection: (xcd, j=bid>>3) -> b=xcd>>1, tib=2j+(xcd&1) in [0,768).
// ---------------------------------------------------------------------------
__global__ __launch_bounds__(256) void attn_kernel(
    const half_t* __restrict__ QKV, half_t* __restrict__ Oa)
{
    __shared__ ShMem shm;
    const int bid = blockIdx.x;
    const int xcd = bid & 7;
    const int b   = xcd >> 1;
    const int tib = ((bid >> 3) << 1) | (xcd & 1);   // token-in-batch [0,768)
    const int g   = tib >> 8;
    const int n   = tib & 255;
    const int t   = (((g << 2) + b) << 8) | n;
    attn_token(shm, QKV, Oa, t);
}

extern "C" void kernel_launch(void* const* d_in, const int* in_sizes, int n_in,
                              void* d_out, int out_size, void* d_ws, size_t ws_size,
                              hipStream_t stream) {
    const float* x   = (const float*)d_in[0];
    const float* wq  = (const float*)d_in[1];
    const float* wkv = (const float*)d_in[2];
    const float* pw  = (const float*)d_in[3];
    const float* pb  = (const float*)d_in[4];
    float* out = (float*)d_out;
    half_t* ws = (half_t*)d_ws;

    half_t* x16   = ws;
    half_t* w3    = x16 + XN;                      // [wq; wkv] = (2304, 768)
    half_t* pw16  = w3 + WQN + WKVN;
    half_t* QKV16 = pw16 + PWN;                    // (3072, 2304)
    half_t* ATT16 = QKV16 + (size_t)Mrows * QKVc;  // (3072, 768)

    const dim3 blk(256);

    // 1. fp32 -> f16 (x + weights); wq/wkv land contiguously in w3
    cvt_all<<<dim3(CVTN / 256), blk, 0, stream>>>(x, wq, wkv, pw, x16, w3, pw16);

    // 2. QKV = x16 @ [wq;wkv]^T — 432 tiles, XCD-chunked
    gemm16<half_t, false><<<dim3((QKVc / 128) * (Mrows / 128)), blk, 0, stream>>>(
        x16, w3, QKV16, nullptr, QKVc, Cc_);

    // 3. attention, batch->XCD-pair swizzled
    attn_kernel<<<dim3(Mrows), blk, 0, stream>>>(QKV16, ATT16);

    // 4. out = ATT16 @ pw16^T + pb — 144 tiles, XCD-chunked
    gemm16<float, true><<<dim3((Cc_ / 128) * (Mrows / 128)), blk, 0, stream>>>(
        ATT16, pw16, out, pb, Cc_, Cc_);
}

// Round 13
// 85.523 us; speedup vs baseline: 2.8586x; 1.1157x over previous
//
#include <hip/hip_runtime.h>
#include <hip/hip_bf16.h>

// Problem constants: B=4, G=3, p=16, N=256, C=768, H=12, D=64
#define Bc 4
#define Gc 3
#define Nc 256
#define Cc_ 768
#define Dc 64
#define Mrows (Bc*Gc*Nc)      // 3072 tokens
#define QKVc (3*Cc_)          // 2304 fused output cols: [q | k | v]
#define Koff Cc_              // k starts at col 768
#define Voff (2*Cc_)          // v starts at col 1536

typedef _Float16 half_t;
typedef __attribute__((ext_vector_type(8))) _Float16 f16x8;
typedef __attribute__((ext_vector_type(4))) float f32x4;

#define XN   (Mrows*Cc_)      // 2359296
#define WQN  (Cc_*Cc_)        // 589824
#define WKVN (2*Cc_*Cc_)      // 1179648
#define PWN  (Cc_*Cc_)        // 589824

// ---------------------------------------------------------------------------
// fp32 -> f16 conversion for x + all three weight matrices, one launch.
// wq16/wkv16 are written CONTIGUOUSLY so they form one (2304,768) weight.
// (round-6 verbatim)
// ---------------------------------------------------------------------------
__global__ __launch_bounds__(256) void cvt_all(
    const float* __restrict__ x, const float* __restrict__ wq,
    const float* __restrict__ wkv, const float* __restrict__ pw,
    half_t* __restrict__ x16, half_t* __restrict__ wq16,
    half_t* __restrict__ wkv16, half_t* __restrict__ pw16)
{
    const size_t e = ((size_t)blockIdx.x * 256 + threadIdx.x) * 8;
    const float* s; half_t* d;
    if (e < XN)                    { s = x   + e;                     d = x16   + e; }
    else if (e < XN + WQN)         { s = wq  + (e - XN);              d = wq16  + (e - XN); }
    else if (e < XN + WQN + WKVN)  { s = wkv + (e - XN - WQN);        d = wkv16 + (e - XN - WQN); }
    else                           { s = pw  + (e - XN - WQN - WKVN); d = pw16  + (e - XN - WQN - WKVN); }
    const float4 a = *(const float4*)s;
    const float4 b = *(const float4*)(s + 4);
    f16x8 o;
    o[0] = (half_t)a.x; o[1] = (half_t)a.y; o[2] = (half_t)a.z; o[3] = (half_t)a.w;
    o[4] = (half_t)b.x; o[5] = (half_t)b.y; o[6] = (half_t)b.z; o[7] = (half_t)b.w;
    *(f16x8*)d = o;
}

// ---------------------------------------------------------------------------
// f16 MFMA GEMM (round-6 verified structure, verbatim):
// C[m][n] = sum_k A[m][k]*W[n][k]  (+ bias[n])
// 128x128 tile, BK=32, 256 thr = 4 waves (2x2 of 64x64), mfma 16x16x32.
// T3/T4-lite: 3 LDS buffers, stage 2 tiles ahead via global_load_lds(16B),
// counted `s_waitcnt vmcnt(4)` + raw s_barrier — never drains vmcnt(0) in
// the main loop. Stage(t+2) issued AFTER the barrier: between barriers waves
// read buf[t%3] and write buf[(t+2)%3] only.
// Failed perturbations (do not retry): TM=64 tile (r7 +6.4us), setprio
// (r7, lockstep = m190 regime), reg-staging cvt-in-GEMM (r9, +34us),
// persistent fusion (r11, +159us), XCD tile swizzle (r12, +10us).
// ---------------------------------------------------------------------------
template<typename OutT, bool BIAS>
__global__ __launch_bounds__(256) void gemm16(
    const half_t* __restrict__ A, const half_t* __restrict__ W,
    OutT* __restrict__ C, const float* __restrict__ bias,
    int M, int Nn, int K)
{
    // [buf][A/B][kgroup][row][8 f16] = 48 KiB
    __shared__ __attribute__((aligned(16))) half_t sm[3][2][4][128][8];

    const int tid = threadIdx.x;
    const int w   = tid >> 6;          // wave 0..3
    const int l   = tid & 63;
    const int wm  = w >> 1;            // m sub-tile
    const int wn  = w & 1;             // n sub-tile
    const int m0  = blockIdx.y << 7;
    const int n0  = blockIdx.x << 7;

    f32x4 acc[4][4] = {};

    // stage one 128x32 A-tile + B-tile: 4 global_load_lds(16B) per thread
    auto stage = [&](int buf, int k0) {
        #pragma unroll
        for (int i = 0; i < 2; ++i) {
            const int c   = w * 2 + i;
            const int kg  = c >> 1;
            const int r0  = (c & 1) * 64;
            const half_t* ga = A + (size_t)(m0 + r0 + l) * K + k0 + kg * 8;
            const half_t* gb = W + (size_t)(n0 + r0 + l) * K + k0 + kg * 8;
            __builtin_amdgcn_global_load_lds(
                (__attribute__((address_space(1))) void*)ga,
                (__attribute__((address_space(3))) void*)&sm[buf][0][kg][r0][0],
                16, 0, 0);
            __builtin_amdgcn_global_load_lds(
                (__attribute__((address_space(1))) void*)gb,
                (__attribute__((address_space(3))) void*)&sm[buf][1][kg][r0][0],
                16, 0, 0);
        }
    };

    const int NT = K >> 5;             // 24 for K=768 (always >= 2 here)
    stage(0, 0);
    stage(1, 32);

    const int kg = l >> 4;             // 0..3
    const int lr = l & 15;
    int cur = 0;

    for (int t = 0; t < NT; ++t) {
        // retire exactly stage(t) (own wave), allow stage(t+1) in flight
        if (t + 1 < NT) asm volatile("s_waitcnt vmcnt(4)" ::: "memory");
        else            asm volatile("s_waitcnt vmcnt(0)" ::: "memory");
        __builtin_amdgcn_s_barrier();
        if (t + 2 < NT) {
            int nb = cur + 2; if (nb >= 3) nb -= 3;
            stage(nb, (t + 2) << 5);
        }

        f16x8 af[4], bf[4];
        #pragma unroll
        for (int mi = 0; mi < 4; ++mi)
            af[mi] = *(const f16x8*)&sm[cur][0][kg][wm * 64 + mi * 16 + lr][0];
        #pragma unroll
        for (int ni = 0; ni < 4; ++ni)
            bf[ni] = *(const f16x8*)&sm[cur][1][kg][wn * 64 + ni * 16 + lr][0];

        #pragma unroll
        for (int mi = 0; mi < 4; ++mi)
            #pragma unroll
            for (int ni = 0; ni < 4; ++ni)
                acc[mi][ni] = __builtin_amdgcn_mfma_f32_16x16x32_f16(
                    af[mi], bf[ni], acc[mi][ni], 0, 0, 0);

        cur = (cur == 2) ? 0 : cur + 1;
    }

    // epilogue: C/D layout col = lane&15, row = (lane>>4)*4 + reg (m89)
    const int lq = l >> 4;
    #pragma unroll
    for (int ni = 0; ni < 4; ++ni) {
        const int gcol = n0 + wn * 64 + ni * 16 + lr;
        const float bv = BIAS ? bias[gcol] : 0.f;
        #pragma unroll
        for (int mi = 0; mi < 4; ++mi) {
            const int grow = m0 + wm * 64 + mi * 16 + lq * 4;
            #pragma unroll
            for (int r = 0; r < 4; ++r)
                C[(size_t)(grow + r) * Nn + gcol] = (OutT)(acc[mi][ni][r] + bv);
        }
    }
}

// ---------------------------------------------------------------------------
// Attention (round-6 verbatim): one block (4 waves) per token t=(g*B+b)*N+n;
// wave handles heads {w, w+4, w+8}. Q/K/V from the fused QKV buffer (f16,
// fp32 math); K/V gathered via the triplane map.
// Failed perturbations (do not retry): head-interleaved ILP (r8, +1.7us),
// token->XCD swizzle (r12), 256-block persistent form (r11).
// ---------------------------------------------------------------------------
__global__ __launch_bounds__(256) void attn_kernel(
    const half_t* __restrict__ QKV,  // (Mrows, 2304) f16 x-order; [q|k|v]
    half_t* __restrict__ Oa)         // (Mrows, C) f16, out-order rows (g,b,n)
{
    const int t  = blockIdx.x;
    const int g  = t >> 10;
    const int b  = (t >> 8) & 3;
    const int n  = t & 255;
    const int a  = n >> 4;
    const int bc = n & 15;

    __shared__ float qs[Cc_];
    __shared__ int   rows[32];

    const int qrow = (b * Gc + g) * Nc + n;
    if (threadIdx.x < 96) {
        const f16x8 v = ((const f16x8*)(QKV + (size_t)qrow * QKVc))[threadIdx.x];
        #pragma unroll
        for (int jj = 0; jj < 8; ++jj) qs[threadIdx.x * 8 + jj] = (float)v[jj];
    }
    if (threadIdx.x < 32) {
        const int j = threadIdx.x;
        int g1 = g + 1; if (g1 >= 3) g1 -= 3;
        int g2 = g + 2; if (g2 >= 3) g2 -= 3;
        rows[j] = (j < 16) ? ((b * Gc + g1) * Nc + a * 16 + j)
                           : ((b * Gc + g2) * Nc + (j - 16) * 16 + bc);
    }
    __syncthreads();

    const int wave = threadIdx.x >> 6;
    const int lane = threadIdx.x & 63;
    const int j    = lane & 31;
    const int dh   = lane >> 5;
    const size_t kvrow = (size_t)rows[j] * QKVc;

    for (int hh = 0; hh < 3; ++hh) {
        const int h = wave + hh * 4;
        // ---- scores: lane=(j ctx, dh half), vectorized f16 K reads ----
        const f16x8* kp = (const f16x8*)(QKV + kvrow + Koff + h * Dc + dh * 32);
        const float* qp = qs + h * Dc + dh * 32;
        float s = 0.f;
        #pragma unroll
        for (int c = 0; c < 4; ++c) {
            const f16x8 k8 = kp[c];
            #pragma unroll
            for (int e = 0; e < 8; ++e) s = fmaf(qp[c * 8 + e], (float)k8[e], s);
        }
        s += __shfl_xor(s, 32);
        s *= 0.125f;                         // 1/sqrt(64)

        // ---- softmax over 32 ctx (halves identical) ----
        float m = s;
        #pragma unroll
        for (int off = 16; off >= 1; off >>= 1) m = fmaxf(m, __shfl_xor(m, off));
        const float e = __expf(s - m);
        float lsum = e;
        #pragma unroll
        for (int off = 16; off >= 1; off >>= 1) lsum += __shfl_xor(lsum, off);
        const float pr = e / lsum;

        // ---- PV: lane = output dim ----
        float o = 0.f;
        #pragma unroll 8
        for (int jj = 0; jj < 32; ++jj) {
            const float pj = __shfl(pr, jj);
            o = fmaf(pj, (float)QKV[(size_t)rows[jj] * QKVc + Voff + h * Dc + lane], o);
        }
        Oa[(size_t)t * Cc_ + h * Dc + lane] = (half_t)o;
    }
}

extern "C" void kernel_launch(void* const* d_in, const int* in_sizes, int n_in,
                              void* d_out, int out_size, void* d_ws, size_t ws_size,
                              hipStream_t stream) {
    const float* x   = (const float*)d_in[0];
    const float* wq  = (const float*)d_in[1];
    const float* wkv = (const float*)d_in[2];
    const float* pw  = (const float*)d_in[3];
    const float* pb  = (const float*)d_in[4];
    float* out = (float*)d_out;

    // f16 workspace (~19 MB used)
    half_t* x16   = (half_t*)d_ws;
    half_t* w3    = x16 + XN;                      // [wq; wkv] = (2304, 768)
    half_t* pw16  = w3 + WQN + WKVN;
    half_t* QKV16 = pw16 + PWN;                    // (3072, 2304)
    half_t* ATT16 = QKV16 + (size_t)Mrows * QKVc;  // (3072, 768)

    const dim3 blk(256);

    // 1. fp32 -> f16 (x + weights); wq/wkv land contiguously in w3
    cvt_all<<<dim3((XN + WQN + WKVN + PWN) / 8 / 256), blk, 0, stream>>>(
        x, wq, wkv, pw, x16, w3, w3 + WQN, pw16);

    // 2. QKV = x16 @ [wq;wkv]^T — one fused GEMM (3072 x 2304 x 768)
    gemm16<half_t, false><<<dim3(QKVc / 128, Mrows / 128), blk, 0, stream>>>(
        x16, w3, QKV16, nullptr, Mrows, QKVc, Cc_);

    // 3. attention with gathered K/V, writes out-order rows (f16)
    attn_kernel<<<dim3(Mrows), blk, 0, stream>>>(QKV16, ATT16);

    // 4. out = ATT16 @ pw16^T + pb  (fp32 epilogue straight into d_out)
    gemm16<float, true><<<dim3(Cc_ / 128, Mrows / 128), blk, 0, stream>>>(
        ATT16, pw16, out, pb, Mrows, Cc_, Cc_);
}